// Round 12
// baseline (440.905 us; speedup 1.0000x reference)
//
#include <hip/hip_runtime.h>
#include <hip/hip_bf16.h>

// Problem constants
#define BQ   8
#define NLQ  1024
#define NQ   2048
#define DQ   128

typedef __attribute__((ext_vector_type(4))) float f32x4;
typedef __attribute__((ext_vector_type(8))) short bf16x8;
typedef __attribute__((ext_vector_type(2))) unsigned long long u64x2;

__device__ __forceinline__ unsigned short bfbits(float f) {
  __hip_bfloat16 h = __float2bfloat16(f);
  return __builtin_bit_cast(unsigned short, h);
}
__device__ __forceinline__ unsigned int pk2(float a, float b) {
  return ((unsigned int)bfbits(b) << 16) | bfbits(a);
}
__device__ __forceinline__ float sigm(float x) { return 1.f / (1.f + expf(-x)); }

// byte permutation within a 128-byte chunk so one ds_read_b128 yields two
// consecutive-kk fp8 MFMA operands (r7-proven).
__device__ __forceinline__ int pi128(int c) {
  return (c & 64) | ((c & 24) << 1) | ((c & 32) >> 2) | (c & 7);
}

// async global->LDS, 16B per lane. LDS dest is wave-uniform base + lane*16.
__device__ __forceinline__ void g2l16(const void* g, void* l) {
  __builtin_amdgcn_global_load_lds(
      (__attribute__((address_space(1))) void*)(uintptr_t)g,
      (__attribute__((address_space(3))) void*)(uint32_t)(uintptr_t)l,
      16, 0, 0);
}

// ---------------------------------------------------------------------------
// Fused step kernel: msgs (fp8, K=2048) + fused-zr + ht (+ optional next-i
// in-proj). 256 blocks x 64 rows x 512 threads (8 waves), 128 KB LDS.
// All wave tiles: wr2 = w>>2 (2 row-groups of 32), wc4 = w&3 (4 col-groups).
//   msgs: 32x32 tiles over 64x128;  zr: 32x64 tiles over 64x256 (one pass!)
//   ht/in: 32x32 tiles over 64x128
// LDS map (128 KB):
//   msgs: As8 3x8K @0..24K, Bs8 3x16K @24..72K
//   gru : At 4x8K @0..32K (tiles 0,1 = h->rh; 2,3 = ms)
//         Bzr 3x32K @32..128K ; zs 16K @112..128K (after zr reads done)
//         Bht 3x16K @32..80K ; Bin 2x16K @32..64K
// ---------------------------------------------------------------------------
template <bool DO_IN, bool LAST>
__global__ __launch_bounds__(512, 1) void step_k(
    const unsigned char* __restrict__ adj8,
    const unsigned char* __restrict__ hT8in,
    unsigned char* __restrict__ hT8out,
    __hip_bfloat16* __restrict__ hbf,
    const __hip_bfloat16* __restrict__ wzr,   // [256][256] block i
    const __hip_bfloat16* __restrict__ htW,   // [128][256]
    const __hip_bfloat16* __restrict__ inWn,  // [128][128] next i (or null)
    const float* __restrict__ ugb, const float* __restrict__ rgb,
    const float* __restrict__ htb, const float* __restrict__ inbn,
    float* __restrict__ hF) {
  __shared__ __align__(16) char smem[131072];
  const int t = threadIdx.x, lane = t & 63, w = t >> 6;   // w in 0..7
  const int wr2 = w >> 2, wc4 = w & 3;
  const int bm = blockIdx.x;
  const int lr = lane & 15, lh = lane >> 4;
  const int rswz8 = (lr & 7) << 4;                        // fp8 byte XOR (read)
  const int rswzH = (lr & 7) << 3;                        // bf16 elem XOR (read)
  const int swzCol = ((lane & 7) ^ (lane >> 3)) << 3;     // bf16 elem (source)
  const int swzB = ((lane & 7) ^ (lane >> 3)) << 4;       // fp8 byte (source)
  const int srow = lane >> 3;

  f32x4 acc[2][4];
#pragma unroll
  for (int m = 0; m < 2; ++m)
#pragma unroll
    for (int n = 0; n < 4; ++n) acc[m][n] = (f32x4){0.f, 0.f, 0.f, 0.f};

  // =================== msgs phase (fp8, nt=16, 3-buffer) ===================
  {
    const int batch = bm >> 5;
    const unsigned char* aB = adj8 + (size_t)batch * NQ * NQ + (size_t)(bm & 31) * 64 * NQ;
    const unsigned char* bB = hT8in + (size_t)batch * DQ * NQ;
    auto As8 = [&](int bi) -> char* { return smem + bi * 8192; };
    auto Bs8 = [&](int bi) -> char* { return smem + 24576 + bi * 16384; };
    auto stage8 = [&](int bi, int tt) {
      const int k = tt * 128;
      g2l16(aB + (size_t)(w * 8 + srow) * NQ + k + swzB, As8(bi) + w * 1024);
#pragma unroll
      for (int q = 0; q < 2; ++q)
        g2l16(bB + (size_t)(w * 16 + q * 8 + srow) * NQ + k + swzB,
              Bs8(bi) + w * 2048 + q * 1024);
    };

    stage8(0, 0);
    stage8(1, 1);
    asm volatile("s_waitcnt vmcnt(3)" ::: "memory");
    __builtin_amdgcn_s_barrier();

    int cur = 0;
    const int nt = 16;  // 2048 / 128
    for (int tt = 0; tt < nt; ++tt) {
      u64x2 av[2][2], bv[2][2];
#pragma unroll
      for (int kk2 = 0; kk2 < 2; ++kk2) {
        const int co = (kk2 * 64 + lh * 16) ^ rswz8;
#pragma unroll
        for (int m = 0; m < 2; ++m)
          av[kk2][m] = *(const u64x2*)(As8(cur) + (wr2 * 32 + m * 16 + lr) * 128 + co);
#pragma unroll
        for (int n = 0; n < 2; ++n)
          bv[kk2][n] = *(const u64x2*)(Bs8(cur) + (wc4 * 32 + n * 16 + lr) * 128 + co);
      }
      if (tt + 2 < nt) {
        int bi = cur + 2; if (bi >= 3) bi -= 3;
        stage8(bi, tt + 2);
      }
      __builtin_amdgcn_s_setprio(1);
#pragma unroll
      for (int kk2 = 0; kk2 < 2; ++kk2)
#pragma unroll
        for (int hf = 0; hf < 2; ++hf)
#pragma unroll
          for (int m = 0; m < 2; ++m)
#pragma unroll
            for (int n = 0; n < 2; ++n)
              acc[m][n] = __builtin_amdgcn_mfma_f32_16x16x32_fp8_fp8(
                  (long)av[kk2][m][hf], (long)bv[kk2][n][hf], acc[m][n], 0, 0, 0);
      __builtin_amdgcn_s_setprio(0);
      if (tt < nt - 2) {
        asm volatile("s_waitcnt vmcnt(3)" ::: "memory");
        __builtin_amdgcn_s_barrier();
      } else if (tt == nt - 2) {
        asm volatile("s_waitcnt vmcnt(0)" ::: "memory");
        __builtin_amdgcn_s_barrier();
      }
      ++cur; if (cur == 3) cur = 0;
    }
  }
  __syncthreads();  // all waves done with msgs LDS, vm drained

  // ===== transition: h -> At tiles 0,1 ; acc(ms) -> tiles 2,3 ; stage zr ====
  __hip_bfloat16* At = (__hip_bfloat16*)smem;               // 4 tiles x 4096 elem
  __hip_bfloat16* zs = (__hip_bfloat16*)(smem + 114688);    // [64][128]
  auto Bzr = [&](int bi) -> __hip_bfloat16* {
    return (__hip_bfloat16*)(smem + 32768 + bi * 32768);
  };
  auto stageZR = [&](int bi, int tt) {
#pragma unroll
    for (int q = 0; q < 4; ++q)
      g2l16(wzr + (size_t)(w * 32 + q * 8 + srow) * 256 + tt * 64 + swzCol,
            (char*)Bzr(bi) + w * 4096 + q * 1024);
  };
#pragma unroll
  for (int ti = 0; ti < 2; ++ti)
    g2l16(hbf + (size_t)(bm * 64 + w * 8 + srow) * 128 + ti * 64 + swzCol,
          smem + ti * 8192 + w * 1024);
  stageZR(0, 0);
  stageZR(1, 1);
  const float DS = 1.f / 8192.f;  // undo adj fp8 scale
#pragma unroll
  for (int m = 0; m < 2; ++m)
#pragma unroll
    for (int n = 0; n < 2; ++n) {
      const int col = wc4 * 32 + n * 16 + lr;               // 0..127
      const int ti = 2 + (col >> 6), cole = col & 63;
#pragma unroll
      for (int r = 0; r < 4; ++r) {
        const int row = wr2 * 32 + m * 16 + lh * 4 + r;
        At[ti * 4096 + row * 64 + (((cole >> 3) ^ (row & 7)) << 3) + (cole & 7)] =
            __float2bfloat16(acc[m][n][r] * DS);
      }
    }
  asm volatile("s_waitcnt vmcnt(4) lgkmcnt(0)" ::: "memory");  // h + zr buf0 done
  __builtin_amdgcn_s_barrier();

  // ======================= fused z|r pass (nt=4, 32KB tiles) ===============
#pragma unroll
  for (int m = 0; m < 2; ++m)
#pragma unroll
    for (int n = 0; n < 4; ++n) acc[m][n] = (f32x4){0.f, 0.f, 0.f, 0.f};
  {
    int cur = 0;
    for (int tt = 0; tt < 4; ++tt) {
      bf16x8 av[2][2], bv[2][4];
#pragma unroll
      for (int kk = 0; kk < 2; ++kk) {
        const int co = (kk * 32 + lh * 8) ^ rswzH;
#pragma unroll
        for (int m = 0; m < 2; ++m)
          av[kk][m] = *(const bf16x8*)&At[tt * 4096 + (wr2 * 32 + m * 16 + lr) * 64 + co];
#pragma unroll
        for (int n = 0; n < 4; ++n)
          bv[kk][n] = *(const bf16x8*)&Bzr(cur)[(wc4 * 64 + n * 16 + lr) * 64 + co];
      }
      if (tt + 2 < 4) {
        int bi = cur + 2; if (bi >= 3) bi -= 3;
        stageZR(bi, tt + 2);
      }
      __builtin_amdgcn_s_setprio(1);
#pragma unroll
      for (int kk = 0; kk < 2; ++kk)
#pragma unroll
        for (int m = 0; m < 2; ++m)
#pragma unroll
          for (int n = 0; n < 4; ++n)
            acc[m][n] = __builtin_amdgcn_mfma_f32_16x16x32_bf16(av[kk][m], bv[kk][n],
                                                                acc[m][n], 0, 0, 0);
      __builtin_amdgcn_s_setprio(0);
      if (tt < 2) {
        asm volatile("s_waitcnt vmcnt(4)" ::: "memory");
        __builtin_amdgcn_s_barrier();
      } else if (tt == 2) {
        asm volatile("s_waitcnt vmcnt(0)" ::: "memory");
        __builtin_amdgcn_s_barrier();
      }
      ++cur; if (cur == 3) cur = 0;
    }
  }
  __builtin_amdgcn_s_barrier();  // all zr reads done before At/zs overwrites

  // ---- zr epilogue: z -> zs slab, r -> rh overwrites h in At (owner-slot).
  //      ht B staging issued first to overlap. ----
  auto Bht = [&](int bi) -> __hip_bfloat16* {
    return (__hip_bfloat16*)(smem + 32768 + bi * 16384);
  };
  auto stageHT = [&](const __hip_bfloat16* BT, int bi, int tt) {
#pragma unroll
    for (int q = 0; q < 2; ++q)
      g2l16(BT + (size_t)(w * 16 + q * 8 + srow) * 256 + tt * 64 + swzCol,
            (char*)Bht(bi) + w * 2048 + q * 1024);
  };
  stageHT(htW, 0, 0);
  stageHT(htW, 1, 1);
  if (wc4 < 2) {  // z outputs: cols 0..127
#pragma unroll
    for (int m = 0; m < 2; ++m)
#pragma unroll
      for (int n = 0; n < 4; ++n) {
        const int col = wc4 * 64 + n * 16 + lr;
        const float zb = ugb[col];
#pragma unroll
        for (int r = 0; r < 4; ++r) {
          const int row = wr2 * 32 + m * 16 + lh * 4 + r;
          zs[row * 128 + col] = __float2bfloat16(sigm(acc[m][n][r] + zb));
        }
      }
  } else {        // r outputs: cols 128..255 -> rh into At tiles 0,1
#pragma unroll
    for (int m = 0; m < 2; ++m)
#pragma unroll
      for (int n = 0; n < 4; ++n) {
        const int c = (wc4 - 2) * 64 + n * 16 + lr;         // 0..127
        const float rb = rgb[c];
        const int ti = c >> 6, cole = c & 63;
#pragma unroll
        for (int r = 0; r < 4; ++r) {
          const int row = wr2 * 32 + m * 16 + lh * 4 + r;
          const int off = ti * 4096 + row * 64 +
                          (((cole >> 3) ^ (row & 7)) << 3) + (cole & 7);
          const float hv = __bfloat162float(At[off]);
          At[off] = __float2bfloat16(sigm(acc[m][n][r] + rb) * hv);
        }
      }
  }
  asm volatile("s_waitcnt vmcnt(2) lgkmcnt(0)" ::: "memory");  // ht buf0 done
  __builtin_amdgcn_s_barrier();

  // ======================= ht pass (nt=4, 16KB tiles, 32x32) ===============
#pragma unroll
  for (int m = 0; m < 2; ++m)
#pragma unroll
    for (int n = 0; n < 4; ++n) acc[m][n] = (f32x4){0.f, 0.f, 0.f, 0.f};
  {
    int cur = 0;
    for (int tt = 0; tt < 4; ++tt) {
      bf16x8 av[2][2], bv[2][2];
#pragma unroll
      for (int kk = 0; kk < 2; ++kk) {
        const int co = (kk * 32 + lh * 8) ^ rswzH;
#pragma unroll
        for (int m = 0; m < 2; ++m)
          av[kk][m] = *(const bf16x8*)&At[tt * 4096 + (wr2 * 32 + m * 16 + lr) * 64 + co];
#pragma unroll
        for (int n = 0; n < 2; ++n)
          bv[kk][n] = *(const bf16x8*)&Bht(cur)[(wc4 * 32 + n * 16 + lr) * 64 + co];
      }
      if (tt + 2 < 4) {
        int bi = cur + 2; if (bi >= 3) bi -= 3;
        stageHT(htW, bi, tt + 2);
      }
      __builtin_amdgcn_s_setprio(1);
#pragma unroll
      for (int kk = 0; kk < 2; ++kk)
#pragma unroll
        for (int m = 0; m < 2; ++m)
#pragma unroll
          for (int n = 0; n < 2; ++n)
            acc[m][n] = __builtin_amdgcn_mfma_f32_16x16x32_bf16(av[kk][m], bv[kk][n],
                                                                acc[m][n], 0, 0, 0);
      __builtin_amdgcn_s_setprio(0);
      if (tt < 2) {
        asm volatile("s_waitcnt vmcnt(2)" ::: "memory");
        __builtin_amdgcn_s_barrier();
      } else if (tt == 2) {
        asm volatile("s_waitcnt vmcnt(0)" ::: "memory");
        __builtin_amdgcn_s_barrier();
      }
      ++cur; if (cur == 3) cur = 0;
    }
  }
  __builtin_amdgcn_s_barrier();  // all ht reads done (At overwrite in DO_IN)

  if constexpr (DO_IN) {
    // stage in-proj B (2 tiles, reuses Bht[0..1] region)
    auto stageIN = [&](int bi, int tt) {
#pragma unroll
      for (int q = 0; q < 2; ++q)
        g2l16(inWn + (size_t)(w * 16 + q * 8 + srow) * 128 + tt * 64 + swzCol,
              (char*)Bht(bi) + w * 2048 + q * 1024);
    };
    stageIN(0, 0);
    stageIN(1, 1);
    // hn -> At tiles 0,1 (owner-slot)
#pragma unroll
    for (int m = 0; m < 2; ++m)
#pragma unroll
      for (int n = 0; n < 2; ++n) {
        const int col = wc4 * 32 + n * 16 + lr;
        const int ti = col >> 6, cole = col & 63;
        const float hb = htb[col];
#pragma unroll
        for (int r = 0; r < 4; ++r) {
          const int row = wr2 * 32 + m * 16 + lh * 4 + r;
          const int gRow = bm * 64 + row;
          const float tv = tanhf(acc[m][n][r] + hb);
          const float zv = __bfloat162float(zs[row * 128 + col]);
          const float hold = __bfloat162float(hbf[(size_t)gRow * DQ + col]);
          const float hn = zv * hold + (1.f - zv) * tv;
          At[ti * 4096 + row * 64 + (((cole >> 3) ^ (row & 7)) << 3) + (cole & 7)] =
              __float2bfloat16(hn);
        }
      }
    asm volatile("s_waitcnt vmcnt(2) lgkmcnt(0)" ::: "memory");
    __builtin_amdgcn_s_barrier();
    // in-proj pass (nt=2)
#pragma unroll
    for (int m = 0; m < 2; ++m)
#pragma unroll
      for (int n = 0; n < 2; ++n) acc[m][n] = (f32x4){0.f, 0.f, 0.f, 0.f};
    for (int tt = 0; tt < 2; ++tt) {
      bf16x8 av[2][2], bv[2][2];
#pragma unroll
      for (int kk = 0; kk < 2; ++kk) {
        const int co = (kk * 32 + lh * 8) ^ rswzH;
#pragma unroll
        for (int m = 0; m < 2; ++m)
          av[kk][m] = *(const bf16x8*)&At[tt * 4096 + (wr2 * 32 + m * 16 + lr) * 64 + co];
#pragma unroll
        for (int n = 0; n < 2; ++n)
          bv[kk][n] = *(const bf16x8*)&Bht(tt)[(wc4 * 32 + n * 16 + lr) * 64 + co];
      }
      __builtin_amdgcn_s_setprio(1);
#pragma unroll
      for (int kk = 0; kk < 2; ++kk)
#pragma unroll
        for (int m = 0; m < 2; ++m)
#pragma unroll
          for (int n = 0; n < 2; ++n)
            acc[m][n] = __builtin_amdgcn_mfma_f32_16x16x32_bf16(av[kk][m], bv[kk][n],
                                                                acc[m][n], 0, 0, 0);
      __builtin_amdgcn_s_setprio(0);
      if (tt == 0) {
        asm volatile("s_waitcnt vmcnt(0)" ::: "memory");
        __builtin_amdgcn_s_barrier();
      }
    }
    // epilogue: h_next = in-proj out -> hbf, hT8out
#pragma unroll
    for (int m = 0; m < 2; ++m)
#pragma unroll
      for (int n = 0; n < 2; ++n) {
        const int col = wc4 * 32 + n * 16 + lr;
        const float ib = inbn[col];
        const int gRow0 = bm * 64 + wr2 * 32 + m * 16 + lh * 4;
        float hv4[4];
#pragma unroll
        for (int r = 0; r < 4; ++r) {
          const float hn = acc[m][n][r] + ib;
          hv4[r] = hn;
          hbf[(size_t)(gRow0 + r) * DQ + col] = __float2bfloat16(hn);
        }
        unsigned int pk = __builtin_amdgcn_cvt_pk_fp8_f32(hv4[0], hv4[1], 0u, false);
        pk = __builtin_amdgcn_cvt_pk_fp8_f32(hv4[2], hv4[3], pk, true);
        const int nl = gRow0 & 2047;
        const int pd = (nl & ~127) | pi128(nl & 127);
        *(unsigned int*)(hT8out + (size_t)(gRow0 >> 11) * (DQ * NQ) +
                         (size_t)col * NQ + pd) = pk;
      }
  } else {
    // final GRU update epilogue
#pragma unroll
    for (int m = 0; m < 2; ++m)
#pragma unroll
      for (int n = 0; n < 2; ++n) {
        const int col = wc4 * 32 + n * 16 + lr;
        const float hb = htb[col];
        const int gRow0 = bm * 64 + wr2 * 32 + m * 16 + lh * 4;
        float hv4[4];
#pragma unroll
        for (int r = 0; r < 4; ++r) {
          const int row = wr2 * 32 + m * 16 + lh * 4 + r;
          const float tv = tanhf(acc[m][n][r] + hb);
          const float zv = __bfloat162float(zs[row * 128 + col]);
          const float hold = __bfloat162float(hbf[(size_t)(gRow0 + r) * DQ + col]);
          const float hn = zv * hold + (1.f - zv) * tv;
          hv4[r] = hn;
          hbf[(size_t)(gRow0 + r) * DQ + col] = __float2bfloat16(hn);
          if constexpr (LAST) hF[(size_t)(gRow0 + r) * DQ + col] = hn;
        }
        unsigned int pk = __builtin_amdgcn_cvt_pk_fp8_f32(hv4[0], hv4[1], 0u, false);
        pk = __builtin_amdgcn_cvt_pk_fp8_f32(hv4[2], hv4[3], pk, true);
        const int nl = gRow0 & 2047;
        const int pd = (nl & ~127) | pi128(nl & 127);
        *(unsigned int*)(hT8out + (size_t)(gRow0 >> 11) * (DQ * NQ) +
                         (size_t)col * NQ + pd) = pk;
      }
  }
}

// ---------------------------------------------------------------------------
// in0: build x (embeddings) into LDS + in-proj block 0. 256 blocks x 64 rows.
// ---------------------------------------------------------------------------
__global__ __launch_bounds__(256, 2) void in0_k(
    const int* __restrict__ node, const int* __restrict__ text,
    const int* __restrict__ line,
    const float* __restrict__ te, const float* __restrict__ te1,
    const __hip_bfloat16* __restrict__ inW, const float* __restrict__ inb,
    __hip_bfloat16* __restrict__ hbf, unsigned char* __restrict__ hT8) {
  __shared__ __align__(16) __hip_bfloat16 Asm[2 * 4096];
  __shared__ __align__(16) __hip_bfloat16 Bsm[2 * 8192];
  const int t = threadIdx.x, lane = t & 63, w = t >> 6;
  const int wr = (w >> 1) & 1, wc = w & 1;
  const int bm = blockIdx.x;
  const int lr = lane & 15, lh = lane >> 4;
  const int rswz = (lr & 7) << 3;
  const int swzCol = ((lane & 7) ^ (lane >> 3)) << 3;
  const int srow = lane >> 3;

#pragma unroll
  for (int bi = 0; bi < 2; ++bi)
#pragma unroll
    for (int q = 0; q < 4; ++q)
      g2l16(inW + (size_t)(w * 32 + q * 8 + srow) * 128 + bi * 64 + swzCol,
            (char*)Bsm + bi * 16384 + w * 4096 + q * 1024);

  {
    const int lrow = t >> 2;             // 0..63
    const int gRow = bm * 64 + lrow;
    const int b = gRow >> 11, p = gRow & 2047;
    const int c0 = (t & 3) * 32;
    float vals[32];
    if (p < NLQ) {
      const int id = node[b * NLQ + p];
      const float tx = (float)text[b * NLQ + p];
#pragma unroll
      for (int j = 0; j < 32; ++j) {
        const int col = c0 + j;
        vals[j] = (col < 127) ? te[(size_t)id * 127 + col] : tx;
      }
    } else {
      const int id = line[b * NLQ + (p - NLQ)];
#pragma unroll
      for (int j = 0; j < 32; ++j) vals[j] = te1[(size_t)id * 128 + c0 + j];
    }
#pragma unroll
    for (int k = 0; k < 4; ++k) {
      const int col = c0 + k * 8;
      const int ti = col >> 6, cole = col & 63;
      uint4 u;
      u.x = pk2(vals[k * 8 + 0], vals[k * 8 + 1]);
      u.y = pk2(vals[k * 8 + 2], vals[k * 8 + 3]);
      u.z = pk2(vals[k * 8 + 4], vals[k * 8 + 5]);
      u.w = pk2(vals[k * 8 + 6], vals[k * 8 + 7]);
      *(uint4*)((char*)Asm + ti * 8192 + lrow * 128 +
                (((cole >> 3) ^ (lrow & 7)) << 4)) = u;
    }
  }
  __syncthreads();

  f32x4 acc[2][4] = {};
  for (int tt = 0; tt < 2; ++tt) {
    bf16x8 av[2][2], bv[2][4];
#pragma unroll
    for (int kk = 0; kk < 2; ++kk) {
#pragma unroll
      for (int m = 0; m < 2; ++m)
        av[kk][m] = *(const bf16x8*)&Asm[tt * 4096 + (wr * 32 + m * 16 + lr) * 64 +
                                        ((kk * 32 + lh * 8) ^ rswz)];
#pragma unroll
      for (int n = 0; n < 4; ++n)
        bv[kk][n] = *(const bf16x8*)&Bsm[tt * 8192 + (wc * 64 + n * 16 + lr) * 64 +
                                         ((kk * 32 + lh * 8) ^ rswz)];
    }
#pragma unroll
    for (int kk = 0; kk < 2; ++kk)
#pragma unroll
      for (int m = 0; m < 2; ++m)
#pragma unroll
        for (int n = 0; n < 4; ++n)
          acc[m][n] = __builtin_amdgcn_mfma_f32_16x16x32_bf16(av[kk][m], bv[kk][n],
                                                              acc[m][n], 0, 0, 0);
  }
#pragma unroll
  for (int m = 0; m < 2; ++m) {
    const int gRow = bm * 64 + wr * 32 + m * 16 + lh * 4;
#pragma unroll
    for (int n = 0; n < 4; ++n) {
      const int col = wc * 64 + n * 16 + lr;
      const float ib = inb[col];
      float hv4[4];
#pragma unroll
      for (int r = 0; r < 4; ++r) {
        const float hn = acc[m][n][r] + ib;
        hv4[r] = hn;
        hbf[(size_t)(gRow + r) * DQ + col] = __float2bfloat16(hn);
      }
      unsigned int pk = __builtin_amdgcn_cvt_pk_fp8_f32(hv4[0], hv4[1], 0u, false);
      pk = __builtin_amdgcn_cvt_pk_fp8_f32(hv4[2], hv4[3], pk, true);
      const int nl = gRow & 2047;
      const int pd = (nl & ~127) | pi128(nl & 127);
      *(unsigned int*)(hT8 + (size_t)(gRow >> 11) * (DQ * NQ) + (size_t)col * NQ + pd) = pk;
    }
  }
}

// ---------------------------------------------------------------------------
// adj fp32 -> fp8 e4m3 x 2^13, pi-permuted per 128-chunk.
__global__ void cvt_adj(const float4* __restrict__ in, unsigned char* __restrict__ out,
                        int n4) {
  int stride = gridDim.x * blockDim.x;
  for (int i = blockIdx.x * blockDim.x + threadIdx.x; i < n4; i += stride) {
    float4 v = in[i];
    unsigned int pk = __builtin_amdgcn_cvt_pk_fp8_f32(v.x * 8192.f, v.y * 8192.f, 0u, false);
    pk = __builtin_amdgcn_cvt_pk_fp8_f32(v.z * 8192.f, v.w * 8192.f, pk, true);
    const int g = i << 2;
    const int dst = (g & ~127) | pi128(g & 127);
    *(unsigned int*)(out + dst) = pk;
  }
}

// Pack weights to bf16, transposed to N x K row-major.
__global__ void pack_weights(const float* __restrict__ ugW, const float* __restrict__ rgW,
                             const float* __restrict__ htW, const float* __restrict__ inW,
                             __hip_bfloat16* __restrict__ wzrT, __hip_bfloat16* __restrict__ htT,
                             __hip_bfloat16* __restrict__ inT) {
  int idx = blockIdx.x * 256 + threadIdx.x;
  if (idx < 5 * 256 * 256) {  // wzrT[i][n][k], n<128 -> ug, else rg
    int i = idx >> 16, r = idx & 65535, nn = r >> 8, k = r & 255;
    float v = (nn < 128) ? ugW[(i * 256 + k) * 128 + nn] : rgW[(i * 256 + k) * 128 + nn - 128];
    wzrT[idx] = __float2bfloat16(v);
    return;
  }
  int j = idx - 5 * 256 * 256;
  if (j < 5 * 128 * 256) {  // htT[i][n][k]
    int i = j >> 15, r = j & 32767, nn = r >> 8, k = r & 255;
    htT[j] = __float2bfloat16(htW[(i * 256 + k) * 128 + nn]);
    return;
  }
  int j2 = j - 5 * 128 * 256;
  if (j2 < 5 * 128 * 128) {  // inT[i][n][k]
    int i = j2 >> 14, r = j2 & 16383, nn = r >> 7, k = r & 127;
    inT[j2] = __float2bfloat16(inW[(i * 128 + k) * 128 + nn]);
  }
}

__device__ __forceinline__ float waveMax(float v) {
#pragma unroll
  for (int m = 32; m; m >>= 1) v = fmaxf(v, __shfl_xor(v, m, 64));
  return v;
}
__device__ __forceinline__ float waveSum(float v) {
#pragma unroll
  for (int m = 32; m; m >>= 1) v += __shfl_xor(v, m, 64);
  return v;
}

// logits + mask + softmax + loss; also copies x rows to outX. 1 row/thread.
__global__ __launch_bounds__(1024) void final_k(const float* __restrict__ h,
                                                const float* __restrict__ w2,
                                                const float* __restrict__ b2,
                                                const int* __restrict__ node,
                                                const float* __restrict__ res,
                                                float* __restrict__ outLoss,
                                                float* __restrict__ outSm,
                                                float* __restrict__ outX) {
  int b = blockIdx.x, t = threadIdx.x;
  __shared__ float lw[128];
  __shared__ float red[16];
  __shared__ float bc;
  if (t < 128) lw[t] = w2[t];
  __syncthreads();
  const float* hr = h + ((size_t)b * NQ + t) * DQ;
  float* xr = outX + ((size_t)b * NLQ + t) * DQ;
  float s = 0.f;
#pragma unroll
  for (int d = 0; d < 128; d += 4) {
    float4 hv = *(const float4*)(hr + d);
    *(float4*)(xr + d) = hv;
    s += hv.x * lw[d] + hv.y * lw[d + 1] + hv.z * lw[d + 2] + hv.w * lw[d + 3];
  }
  float lg = (node[b * NLQ + t] == 2) ? (s + b2[0]) : -1e9f;
  int lane = t & 63, w = t >> 6;
  float mx = waveMax(lg);
  if (lane == 0) red[w] = mx;
  __syncthreads();
  if (t == 0) {
    float m = red[0];
#pragma unroll
    for (int i = 1; i < 16; ++i) m = fmaxf(m, red[i]);
    bc = m;
  }
  __syncthreads();
  float M = bc;
  float e = expf(lg - M);
  float sum = waveSum(e);
  __syncthreads();
  if (lane == 0) red[w] = sum;
  __syncthreads();
  if (t == 0) {
    float tot = 0.f;
#pragma unroll
    for (int i = 0; i < 16; ++i) tot += red[i];
    bc = tot;
  }
  __syncthreads();
  float sm = e / bc;
  outSm[b * NLQ + t] = sm;
  float c = fminf(fmaxf(sm, 1e-10f), 1.f);
  float loss = waveSum(-logf(c) * res[b * NLQ + t]);
  __syncthreads();
  if (lane == 0) red[w] = loss;
  __syncthreads();
  if (t == 0) {
    float tot = 0.f;
#pragma unroll
    for (int i = 0; i < 16; ++i) tot += red[i];
    outLoss[b] = tot;
  }
}

__global__ void ws_fail(float* out) {
  if (threadIdx.x == 0) out[0] = -7.0e7f;  // sentinel: workspace too small
}

// ---------------------------------------------------------------------------
extern "C" void kernel_launch(void* const* d_in, const int* in_sizes, int n_in,
                              void* d_out, int out_size, void* d_ws, size_t ws_size,
                              hipStream_t stream) {
  const int* input_node = (const int*)d_in[0];
  const float* inputad  = (const float*)d_in[2];
  const float* res      = (const float*)d_in[3];
  const int* inputtext  = (const int*)d_in[4];
  const int* linenode   = (const int*)d_in[5];
  const float* tok_emb  = (const float*)d_in[8];
  const float* tok_emb1 = (const float*)d_in[9];
  const float* in_W  = (const float*)d_in[10];
  const float* in_b  = (const float*)d_in[11];
  const float* ug_W  = (const float*)d_in[12];
  const float* ug_b  = (const float*)d_in[13];
  const float* rg_W  = (const float*)d_in[14];
  const float* rg_b  = (const float*)d_in[15];
  const float* ht_W  = (const float*)d_in[16];
  const float* ht_b  = (const float*)d_in[17];
  const float* res2_W = (const float*)d_in[18];
  const float* res2_b = (const float*)d_in[19];

  char* ws = (char*)d_ws;
  const size_t OFF_ADJ = 0;
  const size_t OFF_HBF = OFF_ADJ + (size_t)BQ * NQ * NQ;       // adj fp8, 33.5 MB
  const size_t OFF_HTA = OFF_HBF + (size_t)BQ * NQ * DQ * 2;   // h bf16
  const size_t OFF_HTB = OFF_HTA + (size_t)BQ * NQ * DQ;       // hT8 ping
  const size_t OFF_HF  = OFF_HTB + (size_t)BQ * NQ * DQ;       // hT8 pong
  const size_t OFF_WZR = OFF_HF  + (size_t)BQ * NQ * DQ * 4;   // hF fp32
  const size_t OFF_HTW = OFF_WZR + (size_t)5 * 256 * 256 * 2;
  const size_t OFF_INW = OFF_HTW + (size_t)5 * 128 * 256 * 2;
  const size_t NEED    = OFF_INW + (size_t)5 * 128 * 128 * 2;  // ~52 MB
  if (ws_size < NEED) {
    ws_fail<<<1, 64, 0, stream>>>((float*)d_out);
    return;
  }

  unsigned char* adj8   = (unsigned char*)(ws + OFF_ADJ);
  __hip_bfloat16* hbf   = (__hip_bfloat16*)(ws + OFF_HBF);
  unsigned char* hT8a   = (unsigned char*)(ws + OFF_HTA);
  unsigned char* hT8b   = (unsigned char*)(ws + OFF_HTB);
  float* hF             = (float*)(ws + OFF_HF);
  __hip_bfloat16* wzrT  = (__hip_bfloat16*)(ws + OFF_WZR);
  __hip_bfloat16* htTw  = (__hip_bfloat16*)(ws + OFF_HTW);
  __hip_bfloat16* inTw  = (__hip_bfloat16*)(ws + OFF_INW);

  float* outLoss = (float*)d_out;
  float* outSm = outLoss + BQ;
  float* outX = outSm + BQ * NLQ;

  pack_weights<<<2240, 256, 0, stream>>>(ug_W, rg_W, ht_W, in_W, wzrT, htTw, inTw);
  in0_k<<<256, 256, 0, stream>>>(input_node, inputtext, linenode, tok_emb, tok_emb1,
                                 inTw, in_b, hbf, hT8a);
  cvt_adj<<<4096, 256, 0, stream>>>((const float4*)inputad, adj8,
                                    (int)((size_t)BQ * NQ * NQ / 4));

  unsigned char* rd = hT8a;
  unsigned char* wr = hT8b;
  for (int i = 0; i < 5; ++i) {
    for (int s = 0; s < 3; ++s) {
      const bool doin = (s == 2 && i < 4);
      const bool last = (s == 2 && i == 4);
      if (doin)
        step_k<true, false><<<256, 512, 0, stream>>>(
            adj8, rd, wr, hbf, wzrT + i * 65536, htTw + i * 32768,
            inTw + (i + 1) * 16384, ug_b + i * 128, rg_b + i * 128,
            ht_b + i * 128, in_b + (i + 1) * 128, hF);
      else if (last)
        step_k<false, true><<<256, 512, 0, stream>>>(
            adj8, rd, wr, hbf, wzrT + i * 65536, htTw + i * 32768, nullptr,
            ug_b + i * 128, rg_b + i * 128, ht_b + i * 128, nullptr, hF);
      else
        step_k<false, false><<<256, 512, 0, stream>>>(
            adj8, rd, wr, hbf, wzrT + i * 65536, htTw + i * 32768, nullptr,
            ug_b + i * 128, rg_b + i * 128, ht_b + i * 128, nullptr, hF);
      unsigned char* tmp = rd; rd = wr; wr = tmp;
    }
  }

  final_k<<<8, 1024, 0, stream>>>(hF, res2_W, res2_b, input_node, res,
                                  outLoss, outSm, outX);
}

// Round 13
// 364.190 us; speedup vs baseline: 1.2106x; 1.2106x over previous
//
#include <hip/hip_runtime.h>
#include <hip/hip_bf16.h>

// Problem constants
#define BQ   8
#define NLQ  1024
#define NQ   2048
#define DQ   128

typedef __attribute__((ext_vector_type(4))) float f32x4;
typedef __attribute__((ext_vector_type(8))) short bf16x8;
typedef __attribute__((ext_vector_type(2))) unsigned long long u64x2;

__device__ __forceinline__ unsigned short bfbits(float f) {
  __hip_bfloat16 h = __float2bfloat16(f);
  return __builtin_bit_cast(unsigned short, h);
}
__device__ __forceinline__ unsigned int pk2(float a, float b) {
  return ((unsigned int)bfbits(b) << 16) | bfbits(a);
}
__device__ __forceinline__ float sigm(float x) { return 1.f / (1.f + expf(-x)); }

// byte permutation within a 128-byte chunk so one ds_read_b128 yields two
// consecutive-kk fp8 MFMA operands (r7-proven).
__device__ __forceinline__ int pi128(int c) {
  return (c & 64) | ((c & 24) << 1) | ((c & 32) >> 2) | (c & 7);
}

// async global->LDS, 16B per lane. LDS dest is wave-uniform base + lane*16.
__device__ __forceinline__ void g2l16(const void* g, void* l) {
  __builtin_amdgcn_global_load_lds(
      (__attribute__((address_space(1))) void*)(uintptr_t)g,
      (__attribute__((address_space(3))) void*)(uint32_t)(uintptr_t)l,
      16, 0, 0);
}

// ---------------------------------------------------------------------------
// Fused step kernel, 8-wave (r10-proven, 395us build): msgs (fp8, K=2048,
// in-block) + GRU (+ optional next-i in-proj). 256 blocks x 64 rows x 512
// threads, 80 KB LDS -> 1 block/CU, 8 waves/CU. Block bm's msgs output rows
// == its GRU rows: accumulator goes straight into the GRU A-tiles in LDS.
// hT8 ping-pong carries the cross-block msgs dependency.
// LDS union:
//   msgs: As8 [0,24K) 3x8K fp8, Bs8 [24K,72K) 3x16K fp8
//   gru : At  [0,32K) 4 tiles 64x64 bf16 (0,1=h; 2,3=ms), Bsm [32K,80K) 3x16K
// ---------------------------------------------------------------------------
template <bool DO_IN, bool LAST>
__global__ __launch_bounds__(512, 2) void step_k(
    const unsigned char* __restrict__ adj8,
    const unsigned char* __restrict__ hT8in,
    unsigned char* __restrict__ hT8out,
    __hip_bfloat16* __restrict__ hbf,
    const __hip_bfloat16* __restrict__ wzr,   // [256][256] block i
    const __hip_bfloat16* __restrict__ htW,   // [128][256]
    const __hip_bfloat16* __restrict__ inWn,  // [128][128] next i (or null)
    const float* __restrict__ ugb, const float* __restrict__ rgb,
    const float* __restrict__ htb, const float* __restrict__ inbn,
    float* __restrict__ hF) {
  __shared__ __align__(16) char smem[81920];
  const int t = threadIdx.x, lane = t & 63, w = t >> 6;   // w in 0..7
  const int wr = w >> 1, wc = w & 1;                      // wr in 0..3
  const int bm = blockIdx.x;
  const int lr = lane & 15, lh = lane >> 4;
  const int rswz8 = (lr & 7) << 4;                        // fp8 byte XOR (read)
  const int rswzH = (lr & 7) << 3;                        // bf16 elem XOR (read)
  const int swzCol = ((lane & 7) ^ (lane >> 3)) << 3;     // bf16 elem (source)
  const int swzB = ((lane & 7) ^ (lane >> 3)) << 4;       // fp8 byte (source)
  const int srow = lane >> 3;

  // =================== msgs phase (fp8, nt=16, 3-buffer) ===================
  const int batch = bm >> 5;
  const unsigned char* aB = adj8 + (size_t)batch * NQ * NQ + (size_t)(bm & 31) * 64 * NQ;
  const unsigned char* bB = hT8in + (size_t)batch * DQ * NQ;
  auto As8 = [&](int bi) -> char* { return smem + bi * 8192; };
  auto Bs8 = [&](int bi) -> char* { return smem + 24576 + bi * 16384; };
  auto stage8 = [&](int bi, int tt) {
    const int k = tt * 128;
    g2l16(aB + (size_t)(w * 8 + srow) * NQ + k + swzB, As8(bi) + w * 1024);
#pragma unroll
    for (int q = 0; q < 2; ++q)
      g2l16(bB + (size_t)(w * 16 + q * 8 + srow) * NQ + k + swzB,
            Bs8(bi) + w * 2048 + q * 1024);
  };

  f32x4 acc[4] = {};
  stage8(0, 0);
  stage8(1, 1);
  asm volatile("s_waitcnt vmcnt(3)" ::: "memory");
  __builtin_amdgcn_s_barrier();

  {
    int cur = 0;
    const int nt = 16;  // 2048 / 128
    for (int tt = 0; tt < nt; ++tt) {
      u64x2 av[2], bv[2][4];
#pragma unroll
      for (int kk2 = 0; kk2 < 2; ++kk2) {
        const int co = (kk2 * 64 + lh * 16) ^ rswz8;
        av[kk2] = *(const u64x2*)(As8(cur) + (wr * 16 + lr) * 128 + co);
#pragma unroll
        for (int n = 0; n < 4; ++n)
          bv[kk2][n] = *(const u64x2*)(Bs8(cur) + (wc * 64 + n * 16 + lr) * 128 + co);
      }
      if (tt + 2 < nt) {
        int bi = cur + 2; if (bi >= 3) bi -= 3;
        stage8(bi, tt + 2);
      }
      __builtin_amdgcn_s_setprio(1);
#pragma unroll
      for (int kk2 = 0; kk2 < 2; ++kk2)
#pragma unroll
        for (int hf = 0; hf < 2; ++hf)
#pragma unroll
          for (int n = 0; n < 4; ++n)
            acc[n] = __builtin_amdgcn_mfma_f32_16x16x32_fp8_fp8(
                (long)av[kk2][hf], (long)bv[kk2][n][hf], acc[n], 0, 0, 0);
      __builtin_amdgcn_s_setprio(0);
      if (tt < nt - 2) {
        asm volatile("s_waitcnt vmcnt(3)" ::: "memory");
        __builtin_amdgcn_s_barrier();
      } else if (tt == nt - 2) {
        asm volatile("s_waitcnt vmcnt(0)" ::: "memory");
        __builtin_amdgcn_s_barrier();
      }
      ++cur; if (cur == 3) cur = 0;
    }
  }
  __syncthreads();  // all waves done with msgs LDS

  // ===== transition: h -> tiles 0,1 (g2l16); acc -> tiles 2,3; stage wzr =====
  __hip_bfloat16* At = (__hip_bfloat16*)smem;              // [4][4096]
  __hip_bfloat16* Bsm = (__hip_bfloat16*)(smem + 32768);   // [3][8192]
  auto stageB = [&](const __hip_bfloat16* BT, int ld, int bi, int tt) {
#pragma unroll
    for (int q = 0; q < 2; ++q)
      g2l16(BT + (size_t)(w * 16 + q * 8 + srow) * ld + tt * 64 + swzCol,
            (char*)Bsm + bi * 16384 + w * 2048 + q * 1024);
  };
#pragma unroll
  for (int ti = 0; ti < 2; ++ti)
    g2l16(hbf + (size_t)(bm * 64 + w * 8 + srow) * 128 + ti * 64 + swzCol,
          smem + ti * 8192 + w * 1024);
  stageB(wzr, 256, 0, 0);
  stageB(wzr, 256, 1, 1);
  const float DS = 1.f / 8192.f;  // undo adj fp8 scale
#pragma unroll
  for (int n = 0; n < 4; ++n) {
    const int col = wc * 64 + n * 16 + lr;
    const int ti = 2 + (col >> 6), cole = col & 63;
#pragma unroll
    for (int r = 0; r < 4; ++r) {
      const int row = wr * 16 + lh * 4 + r;
      At[ti * 4096 + row * 64 + (((cole >> 3) ^ (row & 7)) << 3) + (cole & 7)] =
          __float2bfloat16(acc[n][r] * DS);
    }
  }
  asm volatile("s_waitcnt vmcnt(2) lgkmcnt(0)" ::: "memory");
  __builtin_amdgcn_s_barrier();

  // ======================= GRU passes (bf16, r9-proven) ====================
  auto run = [&](const __hip_bfloat16* BT, int ld, int nt2) {
#pragma unroll
    for (int n = 0; n < 4; ++n) acc[n] = (f32x4){0.f, 0.f, 0.f, 0.f};
    int cur = 0;
    for (int tt = 0; tt < nt2; ++tt) {
      bf16x8 av[2], bv[2][4];
#pragma unroll
      for (int kk = 0; kk < 2; ++kk) {
        av[kk] = *(const bf16x8*)&At[tt * 4096 + (wr * 16 + lr) * 64 +
                                     ((kk * 32 + lh * 8) ^ rswzH)];
#pragma unroll
        for (int n = 0; n < 4; ++n)
          bv[kk][n] = *(const bf16x8*)&Bsm[cur * 8192 + (wc * 64 + n * 16 + lr) * 64 +
                                           ((kk * 32 + lh * 8) ^ rswzH)];
      }
      if (tt + 2 < nt2) {
        int bi = cur + 2; if (bi >= 3) bi -= 3;
        stageB(BT, ld, bi, tt + 2);
      }
      __builtin_amdgcn_s_setprio(1);
#pragma unroll
      for (int kk = 0; kk < 2; ++kk)
#pragma unroll
        for (int n = 0; n < 4; ++n)
          acc[n] = __builtin_amdgcn_mfma_f32_16x16x32_bf16(av[kk], bv[kk][n],
                                                           acc[n], 0, 0, 0);
      __builtin_amdgcn_s_setprio(0);
      if (tt < nt2 - 2) {
        asm volatile("s_waitcnt vmcnt(2)" ::: "memory");
        __builtin_amdgcn_s_barrier();
      } else if (tt == nt2 - 2) {
        asm volatile("s_waitcnt vmcnt(0)" ::: "memory");
        __builtin_amdgcn_s_barrier();
      }
      ++cur; if (cur == 3) cur = 0;
    }
  };

  f32x4 zreg[4], hreg[4];

  // ---- pass z ----
  run(wzr, 256, 4);
#pragma unroll
  for (int n = 0; n < 4; ++n) {
    const int col = wc * 64 + n * 16 + lr;
    const float zb = ugb[col];
#pragma unroll
    for (int r = 0; r < 4; ++r) zreg[n][r] = sigm(acc[n][r] + zb);
  }
  __syncthreads();

  // ---- pass r ----
  stageB(wzr + 128 * 256, 256, 0, 0);
  stageB(wzr + 128 * 256, 256, 1, 1);
  asm volatile("s_waitcnt vmcnt(2)" ::: "memory");
  __builtin_amdgcn_s_barrier();
  run(wzr + 128 * 256, 256, 4);
  __syncthreads();  // all waves done reading A tiles 0,1 and Bsm
  stageB(htW, 256, 0, 0);
  stageB(htW, 256, 1, 1);
#pragma unroll
  for (int n = 0; n < 4; ++n) {
    const int col = wc * 64 + n * 16 + lr;
    const int ti = col >> 6, cole = col & 63;
    const float rb = rgb[col];
#pragma unroll
    for (int r = 0; r < 4; ++r) {
      const int lrow = wr * 16 + lh * 4 + r;
      const int off = ti * 4096 + lrow * 64 + (((cole >> 3) ^ (lrow & 7)) << 3) + (cole & 7);
      const float hv = __bfloat162float(At[off]);   // h from LDS
      hreg[n][r] = hv;
      const float rr = sigm(acc[n][r] + rb);
      At[off] = __float2bfloat16(rr * hv);          // same slot, same owner
    }
  }
  asm volatile("s_waitcnt vmcnt(2) lgkmcnt(0)" ::: "memory");
  __builtin_amdgcn_s_barrier();

  // ---- pass ht ----
  run(htW, 256, 4);
  __syncthreads();

  if constexpr (DO_IN) {
    stageB(inWn, 128, 0, 0);
    stageB(inWn, 128, 1, 1);
#pragma unroll
    for (int n = 0; n < 4; ++n) {
      const int col = wc * 64 + n * 16 + lr;
      const int ti = col >> 6, cole = col & 63;
      const float hb = htb[col];
#pragma unroll
      for (int r = 0; r < 4; ++r) {
        const int lrow = wr * 16 + lh * 4 + r;
        const float tv = tanhf(acc[n][r] + hb);
        const float zv = zreg[n][r];
        const float hn = zv * hreg[n][r] + (1.f - zv) * tv;
        At[ti * 4096 + lrow * 64 + (((cole >> 3) ^ (lrow & 7)) << 3) + (cole & 7)] =
            __float2bfloat16(hn);
      }
    }
    asm volatile("s_waitcnt vmcnt(2) lgkmcnt(0)" ::: "memory");
    __builtin_amdgcn_s_barrier();
    // ---- pass in-proj (next block) ----
    run(inWn, 128, 2);
    const int gRow = bm * 64 + wr * 16 + lh * 4;
#pragma unroll
    for (int n = 0; n < 4; ++n) {
      const int col = wc * 64 + n * 16 + lr;
      const float ib = inbn[col];
      float hv4[4];
#pragma unroll
      for (int r = 0; r < 4; ++r) {
        const float hn = acc[n][r] + ib;
        hv4[r] = hn;
        hbf[(size_t)(gRow + r) * DQ + col] = __float2bfloat16(hn);
      }
      unsigned int pk = __builtin_amdgcn_cvt_pk_fp8_f32(hv4[0], hv4[1], 0u, false);
      pk = __builtin_amdgcn_cvt_pk_fp8_f32(hv4[2], hv4[3], pk, true);
      const int nl = gRow & 2047;
      const int pd = (nl & ~127) | pi128(nl & 127);
      *(unsigned int*)(hT8out + (size_t)(gRow >> 11) * (DQ * NQ) + (size_t)col * NQ + pd) = pk;
    }
  } else {
    const int gRow = bm * 64 + wr * 16 + lh * 4;
#pragma unroll
    for (int n = 0; n < 4; ++n) {
      const int col = wc * 64 + n * 16 + lr;
      const float hb = htb[col];
      float hv4[4];
#pragma unroll
      for (int r = 0; r < 4; ++r) {
        const float tv = tanhf(acc[n][r] + hb);
        const float zv = zreg[n][r];
        const float hn = zv * hreg[n][r] + (1.f - zv) * tv;
        hv4[r] = hn;
        hbf[(size_t)(gRow + r) * DQ + col] = __float2bfloat16(hn);
        if constexpr (LAST) hF[(size_t)(gRow + r) * DQ + col] = hn;
      }
      unsigned int pk = __builtin_amdgcn_cvt_pk_fp8_f32(hv4[0], hv4[1], 0u, false);
      pk = __builtin_amdgcn_cvt_pk_fp8_f32(hv4[2], hv4[3], pk, true);
      const int nl = gRow & 2047;
      const int pd = (nl & ~127) | pi128(nl & 127);
      *(unsigned int*)(hT8out + (size_t)(gRow >> 11) * (DQ * NQ) + (size_t)col * NQ + pd) = pk;
    }
  }
}

// ---------------------------------------------------------------------------
// in0: build x (embeddings) into LDS + in-proj block 0. 256 blocks x 64 rows.
// ---------------------------------------------------------------------------
__global__ __launch_bounds__(256, 2) void in0_k(
    const int* __restrict__ node, const int* __restrict__ text,
    const int* __restrict__ line,
    const float* __restrict__ te, const float* __restrict__ te1,
    const __hip_bfloat16* __restrict__ inW, const float* __restrict__ inb,
    __hip_bfloat16* __restrict__ hbf, unsigned char* __restrict__ hT8) {
  __shared__ __align__(16) __hip_bfloat16 Asm[2 * 4096];
  __shared__ __align__(16) __hip_bfloat16 Bsm[2 * 8192];
  const int t = threadIdx.x, lane = t & 63, w = t >> 6;
  const int wr = (w >> 1) & 1, wc = w & 1;
  const int bm = blockIdx.x;
  const int lr = lane & 15, lh = lane >> 4;
  const int rswz = (lr & 7) << 3;
  const int swzCol = ((lane & 7) ^ (lane >> 3)) << 3;
  const int srow = lane >> 3;

#pragma unroll
  for (int bi = 0; bi < 2; ++bi)
#pragma unroll
    for (int q = 0; q < 4; ++q)
      g2l16(inW + (size_t)(w * 32 + q * 8 + srow) * 128 + bi * 64 + swzCol,
            (char*)Bsm + bi * 16384 + w * 4096 + q * 1024);

  {
    const int lrow = t >> 2;             // 0..63
    const int gRow = bm * 64 + lrow;
    const int b = gRow >> 11, p = gRow & 2047;
    const int c0 = (t & 3) * 32;
    float vals[32];
    if (p < NLQ) {
      const int id = node[b * NLQ + p];
      const float tx = (float)text[b * NLQ + p];
#pragma unroll
      for (int j = 0; j < 32; ++j) {
        const int col = c0 + j;
        vals[j] = (col < 127) ? te[(size_t)id * 127 + col] : tx;
      }
    } else {
      const int id = line[b * NLQ + (p - NLQ)];
#pragma unroll
      for (int j = 0; j < 32; ++j) vals[j] = te1[(size_t)id * 128 + c0 + j];
    }
#pragma unroll
    for (int k = 0; k < 4; ++k) {
      const int col = c0 + k * 8;
      const int ti = col >> 6, cole = col & 63;
      uint4 u;
      u.x = pk2(vals[k * 8 + 0], vals[k * 8 + 1]);
      u.y = pk2(vals[k * 8 + 2], vals[k * 8 + 3]);
      u.z = pk2(vals[k * 8 + 4], vals[k * 8 + 5]);
      u.w = pk2(vals[k * 8 + 6], vals[k * 8 + 7]);
      *(uint4*)((char*)Asm + ti * 8192 + lrow * 128 +
                (((cole >> 3) ^ (lrow & 7)) << 4)) = u;
    }
  }
  __syncthreads();

  f32x4 acc[2][4] = {};
  for (int tt = 0; tt < 2; ++tt) {
    bf16x8 av[2][2], bv[2][4];
#pragma unroll
    for (int kk = 0; kk < 2; ++kk) {
#pragma unroll
      for (int m = 0; m < 2; ++m)
        av[kk][m] = *(const bf16x8*)&Asm[tt * 4096 + (wr * 32 + m * 16 + lr) * 64 +
                                        ((kk * 32 + lh * 8) ^ rswz)];
#pragma unroll
      for (int n = 0; n < 4; ++n)
        bv[kk][n] = *(const bf16x8*)&Bsm[tt * 8192 + (wc * 64 + n * 16 + lr) * 64 +
                                         ((kk * 32 + lh * 8) ^ rswz)];
    }
#pragma unroll
    for (int kk = 0; kk < 2; ++kk)
#pragma unroll
      for (int m = 0; m < 2; ++m)
#pragma unroll
        for (int n = 0; n < 4; ++n)
          acc[m][n] = __builtin_amdgcn_mfma_f32_16x16x32_bf16(av[kk][m], bv[kk][n],
                                                              acc[m][n], 0, 0, 0);
  }
#pragma unroll
  for (int m = 0; m < 2; ++m) {
    const int gRow = bm * 64 + wr * 32 + m * 16 + lh * 4;
#pragma unroll
    for (int n = 0; n < 4; ++n) {
      const int col = wc * 64 + n * 16 + lr;
      const float ib = inb[col];
      float hv4[4];
#pragma unroll
      for (int r = 0; r < 4; ++r) {
        const float hn = acc[m][n][r] + ib;
        hv4[r] = hn;
        hbf[(size_t)(gRow + r) * DQ + col] = __float2bfloat16(hn);
      }
      unsigned int pk = __builtin_amdgcn_cvt_pk_fp8_f32(hv4[0], hv4[1], 0u, false);
      pk = __builtin_amdgcn_cvt_pk_fp8_f32(hv4[2], hv4[3], pk, true);
      const int nl = gRow & 2047;
      const int pd = (nl & ~127) | pi128(nl & 127);
      *(unsigned int*)(hT8 + (size_t)(gRow >> 11) * (DQ * NQ) + (size_t)col * NQ + pd) = pk;
    }
  }
}

// ---------------------------------------------------------------------------
// adj fp32 -> fp8 e4m3 x 2^13, pi-permuted per 128-chunk.
__global__ void cvt_adj(const float4* __restrict__ in, unsigned char* __restrict__ out,
                        int n4) {
  int stride = gridDim.x * blockDim.x;
  for (int i = blockIdx.x * blockDim.x + threadIdx.x; i < n4; i += stride) {
    float4 v = in[i];
    unsigned int pk = __builtin_amdgcn_cvt_pk_fp8_f32(v.x * 8192.f, v.y * 8192.f, 0u, false);
    pk = __builtin_amdgcn_cvt_pk_fp8_f32(v.z * 8192.f, v.w * 8192.f, pk, true);
    const int g = i << 2;
    const int dst = (g & ~127) | pi128(g & 127);
    *(unsigned int*)(out + dst) = pk;
  }
}

// Pack weights to bf16, transposed to N x K row-major.
__global__ void pack_weights(const float* __restrict__ ugW, const float* __restrict__ rgW,
                             const float* __restrict__ htW, const float* __restrict__ inW,
                             __hip_bfloat16* __restrict__ wzrT, __hip_bfloat16* __restrict__ htT,
                             __hip_bfloat16* __restrict__ inT) {
  int idx = blockIdx.x * 256 + threadIdx.x;
  if (idx < 5 * 256 * 256) {  // wzrT[i][n][k], n<128 -> ug, else rg
    int i = idx >> 16, r = idx & 65535, nn = r >> 8, k = r & 255;
    float v = (nn < 128) ? ugW[(i * 256 + k) * 128 + nn] : rgW[(i * 256 + k) * 128 + nn - 128];
    wzrT[idx] = __float2bfloat16(v);
    return;
  }
  int j = idx - 5 * 256 * 256;
  if (j < 5 * 128 * 256) {  // htT[i][n][k]
    int i = j >> 15, r = j & 32767, nn = r >> 8, k = r & 255;
    htT[j] = __float2bfloat16(htW[(i * 256 + k) * 128 + nn]);
    return;
  }
  int j2 = j - 5 * 128 * 256;
  if (j2 < 5 * 128 * 128) {  // inT[i][n][k]
    int i = j2 >> 14, r = j2 & 16383, nn = r >> 7, k = r & 127;
    inT[j2] = __float2bfloat16(inW[(i * 128 + k) * 128 + nn]);
  }
}

__device__ __forceinline__ float waveMax(float v) {
#pragma unroll
  for (int m = 32; m; m >>= 1) v = fmaxf(v, __shfl_xor(v, m, 64));
  return v;
}
__device__ __forceinline__ float waveSum(float v) {
#pragma unroll
  for (int m = 32; m; m >>= 1) v += __shfl_xor(v, m, 64);
  return v;
}

// logits + mask + softmax + loss. 1 row/thread, 8 blocks x 1024.
__global__ __launch_bounds__(1024) void final_k(const float* __restrict__ h,
                                                const float* __restrict__ w2,
                                                const float* __restrict__ b2,
                                                const int* __restrict__ node,
                                                const float* __restrict__ res,
                                                float* __restrict__ outLoss,
                                                float* __restrict__ outSm) {
  int b = blockIdx.x, t = threadIdx.x;
  __shared__ float lw[128];
  __shared__ float red[16];
  __shared__ float bc;
  if (t < 128) lw[t] = w2[t];
  __syncthreads();
  const float* hr = h + ((size_t)b * NQ + t) * DQ;
  float s = 0.f;
#pragma unroll
  for (int d = 0; d < 128; d += 4) {
    float4 hv = *(const float4*)(hr + d);
    s += hv.x * lw[d] + hv.y * lw[d + 1] + hv.z * lw[d + 2] + hv.w * lw[d + 3];
  }
  float lg = (node[b * NLQ + t] == 2) ? (s + b2[0]) : -1e9f;
  int lane = t & 63, w = t >> 6;
  float mx = waveMax(lg);
  if (lane == 0) red[w] = mx;
  __syncthreads();
  if (t == 0) {
    float m = red[0];
#pragma unroll
    for (int i = 1; i < 16; ++i) m = fmaxf(m, red[i]);
    bc = m;
  }
  __syncthreads();
  float M = bc;
  float e = expf(lg - M);
  float sum = waveSum(e);
  __syncthreads();
  if (lane == 0) red[w] = sum;
  __syncthreads();
  if (t == 0) {
    float tot = 0.f;
#pragma unroll
    for (int i = 0; i < 16; ++i) tot += red[i];
    bc = tot;
  }
  __syncthreads();
  float sm = e / bc;
  outSm[b * NLQ + t] = sm;
  float c = fminf(fmaxf(sm, 1e-10f), 1.f);
  float loss = waveSum(-logf(c) * res[b * NLQ + t]);
  __syncthreads();
  if (lane == 0) red[w] = loss;
  __syncthreads();
  if (t == 0) {
    float tot = 0.f;
#pragma unroll
    for (int i = 0; i < 16; ++i) tot += red[i];
    outLoss[b] = tot;
  }
}

// x output copy: 8 MB fp32, machine-wide grid.
__global__ void copy_x(const float4* __restrict__ h, float4* __restrict__ out) {
  int idx = blockIdx.x * 256 + threadIdx.x;  // 8*1024*32 = 262144 exactly
  int r = idx >> 5;
  int c = idx & 31;
  int b = r >> 10, n = r & 1023;
  out[idx] = h[((size_t)b * NQ + n) * 32 + c];
}

__global__ void ws_fail(float* out) {
  if (threadIdx.x == 0) out[0] = -7.0e7f;  // sentinel: workspace too small
}

// ---------------------------------------------------------------------------
extern "C" void kernel_launch(void* const* d_in, const int* in_sizes, int n_in,
                              void* d_out, int out_size, void* d_ws, size_t ws_size,
                              hipStream_t stream) {
  const int* input_node = (const int*)d_in[0];
  const float* inputad  = (const float*)d_in[2];
  const float* res      = (const float*)d_in[3];
  const int* inputtext  = (const int*)d_in[4];
  const int* linenode   = (const int*)d_in[5];
  const float* tok_emb  = (const float*)d_in[8];
  const float* tok_emb1 = (const float*)d_in[9];
  const float* in_W  = (const float*)d_in[10];
  const float* in_b  = (const float*)d_in[11];
  const float* ug_W  = (const float*)d_in[12];
  const float* ug_b  = (const float*)d_in[13];
  const float* rg_W  = (const float*)d_in[14];
  const float* rg_b  = (const float*)d_in[15];
  const float* ht_W  = (const float*)d_in[16];
  const float* ht_b  = (const float*)d_in[17];
  const float* res2_W = (const float*)d_in[18];
  const float* res2_b = (const float*)d_in[19];

  char* ws = (char*)d_ws;
  const size_t OFF_ADJ = 0;
  const size_t OFF_HBF = OFF_ADJ + (size_t)BQ * NQ * NQ;       // adj fp8, 33.5 MB
  const size_t OFF_HTA = OFF_HBF + (size_t)BQ * NQ * DQ * 2;   // h bf16
  const size_t OFF_HTB = OFF_HTA + (size_t)BQ * NQ * DQ;       // hT8 ping
  const size_t OFF_HF  = OFF_HTB + (size_t)BQ * NQ * DQ;       // hT8 pong
  const size_t OFF_WZR = OFF_HF  + (size_t)BQ * NQ * DQ * 4;   // hF fp32
  const size_t OFF_HTW = OFF_WZR + (size_t)5 * 256 * 256 * 2;
  const size_t OFF_INW = OFF_HTW + (size_t)5 * 128 * 256 * 2;
  const size_t NEED    = OFF_INW + (size_t)5 * 128 * 128 * 2;  // ~52 MB
  if (ws_size < NEED) {
    ws_fail<<<1, 64, 0, stream>>>((float*)d_out);
    return;
  }

  unsigned char* adj8   = (unsigned char*)(ws + OFF_ADJ);
  __hip_bfloat16* hbf   = (__hip_bfloat16*)(ws + OFF_HBF);
  unsigned char* hT8a   = (unsigned char*)(ws + OFF_HTA);
  unsigned char* hT8b   = (unsigned char*)(ws + OFF_HTB);
  float* hF             = (float*)(ws + OFF_HF);
  __hip_bfloat16* wzrT  = (__hip_bfloat16*)(ws + OFF_WZR);
  __hip_bfloat16* htTw  = (__hip_bfloat16*)(ws + OFF_HTW);
  __hip_bfloat16* inTw  = (__hip_bfloat16*)(ws + OFF_INW);

  float* outLoss = (float*)d_out;
  float* outSm = outLoss + BQ;
  float* outX = outSm + BQ * NLQ;

  pack_weights<<<2240, 256, 0, stream>>>(ug_W, rg_W, ht_W, in_W, wzrT, htTw, inTw);
  in0_k<<<256, 256, 0, stream>>>(input_node, inputtext, linenode, tok_emb, tok_emb1,
                                 inTw, in_b, hbf, hT8a);
  cvt_adj<<<4096, 256, 0, stream>>>((const float4*)inputad, adj8,
                                    (int)((size_t)BQ * NQ * NQ / 4));

  unsigned char* rd = hT8a;
  unsigned char* wr = hT8b;
  for (int i = 0; i < 5; ++i) {
    for (int s = 0; s < 3; ++s) {
      const bool doin = (s == 2 && i < 4);
      const bool last = (s == 2 && i == 4);
      if (doin)
        step_k<true, false><<<256, 512, 0, stream>>>(
            adj8, rd, wr, hbf, wzrT + i * 65536, htTw + i * 32768,
            inTw + (i + 1) * 16384, ug_b + i * 128, rg_b + i * 128,
            ht_b + i * 128, in_b + (i + 1) * 128, hF);
      else if (last)
        step_k<false, true><<<256, 512, 0, stream>>>(
            adj8, rd, wr, hbf, wzrT + i * 65536, htTw + i * 32768, nullptr,
            ug_b + i * 128, rg_b + i * 128, ht_b + i * 128, nullptr, hF);
      else
        step_k<false, false><<<256, 512, 0, stream>>>(
            adj8, rd, wr, hbf, wzrT + i * 65536, htTw + i * 32768, nullptr,
            ug_b + i * 128, rg_b + i * 128, ht_b + i * 128, nullptr, hF);
      unsigned char* tmp = rd; rd = wr; wr = tmp;
    }
  }

  final_k<<<8, 1024, 0, stream>>>(hF, res2_W, res2_b, input_node, res,
                                  outLoss, outSm);
  copy_x<<<1024, 256, 0, stream>>>((const float4*)hF, (float4*)outX);
}